// Round 6
// baseline (142.061 us; speedup 1.0000x reference)
//
#include <hip/hip_runtime.h>

// B=1e6 rows, N=64 heads, D=3.
// u[b,n,k] = tanh(x[b,:]·W[n,k,:] + bias[n,k]); out_k[b] = sum_n u[b,n,k]*c_k[n].
// d_out: [0..B)=rho, [B..2B)=p, [2B..3B)=u  (f32).
//
// tanh via Eigen/XLA rational minimax: tanh(h) ~= h*P6(h^2)/Q3(h^2), |h| clamped
// to 7.90531. ONE v_rcp_f32 per row-pair serves all 6 denominators:
// 1/d_i = (prod_{j!=i} d_j) * rcp(prod_j d_j). dens in [0.0049, 0.91] -> no
// under/overflow (min product 1.4e-14).

#define NN   64
#define RPT  2
#define BLK  256

typedef float f2 __attribute__((ext_vector_type(2)));

__device__ __forceinline__ f2 mk2(float a, float b) { f2 r; r.x = a; r.y = b; return r; }
__device__ __forceinline__ f2 pkfma(f2 a, f2 b, f2 c) { return __builtin_elementwise_fma(a, b, c); }
__device__ __forceinline__ f2 pkmin(f2 a, f2 b) { return __builtin_elementwise_min(a, b); }
__device__ __forceinline__ f2 pkmax(f2 a, f2 b) { return __builtin_elementwise_max(a, b); }

__device__ __forceinline__ float frcp(float x) {
#if __has_builtin(__builtin_amdgcn_rcpf)
    return __builtin_amdgcn_rcpf(x);
#else
    return 1.0f / x;
#endif
}

// Eigen generic_fast_tanh_float constants (also used by XLA/ORT).
#define A1  4.89352455891786e-03f
#define A3  6.37261928875436e-04f
#define A5  1.48572235717979e-05f
#define A7  5.12229709037114e-08f
#define A9  (-8.60467152213735e-11f)
#define A11 2.00018790482477e-13f
#define A13 (-2.76076847742355e-16f)
#define B0  4.89352518554385e-03f
#define B2  2.26843463243900e-03f
#define B4  1.18534705686654e-04f
#define B6  1.19825839466702e-06f
#define CLAMP 7.90531110763549f

__device__ __forceinline__ void tanh_num_den(f2 h, f2& num, f2& den) {
    const f2 s = h * h;
    f2 p = mk2(A13, A13);
    p = pkfma(s, p, mk2(A11, A11));
    p = pkfma(s, p, mk2(A9,  A9));
    p = pkfma(s, p, mk2(A7,  A7));
    p = pkfma(s, p, mk2(A5,  A5));
    p = pkfma(s, p, mk2(A3,  A3));
    p = pkfma(s, p, mk2(A1,  A1));
    num = p * h;
    f2 q = mk2(B6, B6);
    q = pkfma(s, q, mk2(B4, B4));
    q = pkfma(s, q, mk2(B2, B2));
    q = pkfma(s, q, mk2(B0, B0));
    den = q;
}

__global__ __launch_bounds__(BLK) void fused_tanh_heads(
    const float* __restrict__ x,     // [B,3]
    const float* __restrict__ W,     // [64,3,3]
    const float* __restrict__ bias,  // [64,3]
    const float* __restrict__ c_rho, // [64]
    const float* __restrict__ c_p,   // [64]
    const float* __restrict__ c_u,   // [64]
    float* __restrict__ out,         // [3*B]
    int B)
{
    // Per-n record: 32 floats, pair-splatted: {W[9]x2, b[3]x2, crho x2, cp x2,
    // cu x2, pad x2} -> 8 float4 broadcast reads per n.
    __shared__ float sc[NN * 32];
    const int t = threadIdx.x;
    // Bank-conflict-free fill: lane t writes idx = t + 256k (bank = t%32).
    #pragma unroll
    for (int k = 0; k < 8; ++k) {
        const int idx = t + BLK * k;   // 0..2047
        const int n = idx >> 5;
        const int o = idx & 31;
        float v;
        if (o < 18)      v = W[n * 9 + (o >> 1)];
        else if (o < 24) v = bias[n * 3 + ((o - 18) >> 1)];
        else if (o < 26) v = c_rho[n];
        else if (o < 28) v = c_p[n];
        else if (o < 30) v = c_u[n];
        else             v = 0.0f;
        sc[idx] = v;
    }
    __syncthreads();

    const int r0 = blockIdx.x * (BLK * RPT) + t;
    const int r1 = r0 + BLK;
    const bool ok0 = (r0 < B), ok1 = (r1 < B);

    const f2 X0 = mk2(ok0 ? x[r0 * 3 + 0] : 0.0f, ok1 ? x[r1 * 3 + 0] : 0.0f);
    const f2 X1 = mk2(ok0 ? x[r0 * 3 + 1] : 0.0f, ok1 ? x[r1 * 3 + 1] : 0.0f);
    const f2 X2 = mk2(ok0 ? x[r0 * 3 + 2] : 0.0f, ok1 ? x[r1 * 3 + 2] : 0.0f);

    f2 acc0 = mk2(0.0f, 0.0f), acc1 = acc0, acc2 = acc0;
    const f2 cpos = mk2(CLAMP, CLAMP), cneg = mk2(-CLAMP, -CLAMP);

    const float4* q4 = (const float4*)sc;
    #pragma unroll 2
    for (int n = 0; n < NN; ++n) {
        const float4 Q0 = q4[n * 8 + 0];  // w00 w01
        const float4 Q1 = q4[n * 8 + 1];  // w02 w10
        const float4 Q2 = q4[n * 8 + 2];  // w11 w12
        const float4 Q3 = q4[n * 8 + 3];  // w20 w21
        const float4 Q4 = q4[n * 8 + 4];  // w22 b0
        const float4 Q5 = q4[n * 8 + 5];  // b1  b2
        const float4 Q6 = q4[n * 8 + 6];  // crho cp
        const float4 Q7 = q4[n * 8 + 7];  // cu  pad

        f2 h0 = pkfma(X2, mk2(Q1.x, Q1.y),
                 pkfma(X1, mk2(Q0.z, Q0.w),
                  pkfma(X0, mk2(Q0.x, Q0.y), mk2(Q4.z, Q4.w))));
        f2 h1 = pkfma(X2, mk2(Q2.z, Q2.w),
                 pkfma(X1, mk2(Q2.x, Q2.y),
                  pkfma(X0, mk2(Q1.z, Q1.w), mk2(Q5.x, Q5.y))));
        f2 h2 = pkfma(X2, mk2(Q4.x, Q4.y),
                 pkfma(X1, mk2(Q3.z, Q3.w),
                  pkfma(X0, mk2(Q3.x, Q3.y), mk2(Q5.z, Q5.w))));

        h0 = pkmin(cpos, pkmax(cneg, h0));
        h1 = pkmin(cpos, pkmax(cneg, h1));
        h2 = pkmin(cpos, pkmax(cneg, h2));

        f2 n0, d0, n1, d1, n2, d2;
        tanh_num_den(h0, n0, d0);
        tanh_num_den(h1, n1, d1);
        tanh_num_den(h2, n2, d2);

        // one rcp for all 6 denominators
        const f2 D01 = d0 * d1;
        const f2 D12 = d1 * d2;
        const f2 D02 = d0 * d2;
        const f2 T   = D01 * d2;        // (t_row0, t_row1)
        const float g = T.x * T.y;
        const float R = frcp(g);
        const f2 Rp = mk2(R * T.y, R * T.x);   // (1/t_row0, 1/t_row1)
        const f2 I0 = D12 * Rp;
        const f2 I1 = D02 * Rp;
        const f2 I2 = D01 * Rp;

        acc0 = pkfma(n0 * I0, mk2(Q6.x, Q6.y), acc0);
        acc1 = pkfma(n1 * I1, mk2(Q6.z, Q6.w), acc1);
        acc2 = pkfma(n2 * I2, mk2(Q7.x, Q7.y), acc2);
    }

    if (ok0) {
        out[r0]         = acc0.x;
        out[B + r0]     = acc1.x;
        out[2 * B + r0] = acc2.x;
    }
    if (ok1) {
        out[r1]         = acc0.y;
        out[B + r1]     = acc1.y;
        out[2 * B + r1] = acc2.y;
    }
}

extern "C" void kernel_launch(void* const* d_in, const int* in_sizes, int n_in,
                              void* d_out, int out_size, void* d_ws, size_t ws_size,
                              hipStream_t stream) {
    (void)d_ws; (void)ws_size; (void)n_in; (void)out_size;
    const float* x     = (const float*)d_in[0];
    const float* W     = (const float*)d_in[1];
    const float* bias  = (const float*)d_in[2];
    const float* c_rho = (const float*)d_in[3];
    const float* c_p   = (const float*)d_in[4];
    const float* c_u   = (const float*)d_in[5];
    float* out = (float*)d_out;

    const int B = in_sizes[0] / 3;
    const int rows_per_block = BLK * RPT;
    const int grid = (B + rows_per_block - 1) / rows_per_block;

    fused_tanh_heads<<<grid, BLK, 0, stream>>>(x, W, bias, c_rho, c_p, c_u, out, B);
}

// Round 7
// 126.060 us; speedup vs baseline: 1.1269x; 1.1269x over previous
//
#include <hip/hip_runtime.h>

// B=1e6 rows, N=64 heads, D=3.
// u[b,n,k] = tanh(x[b,:]·W[n,k,:] + bias[n,k]); out_k[b] = sum_n u[b,n,k]*c_k[n].
// d_out: [0..B)=rho, [B..2B)=p, [2B..3B)=u  (f32).
//
// tanh(h) = 1 - 2/(1+exp2(K*h)), K=2*log2(e), K folded into W,b at LDS-fill.
// Fold further: out_k = C_k - 2 * sum_n c_k[n] * inv_k[n],  C_k = sum_n c_k[n].
// One rcp per row serves all 3 channels: inv_i = (prod_{j!=i} a_j)*rcp(prod a_j).
// NOTE (gfx950 model, calibrated R2/R4): fp32 VALU = 2 cyc/wave-instr whether
// packed or not (157.3 TF spec == scalar rate); trans (exp2/rcp) ~8.5 cyc.
// So we minimize OP COUNT, not "packedness". Scalar code on purpose.

#define NN   64
#define RPT  4
#define BLK  256

__device__ __forceinline__ float fexp2(float x) {
#if __has_builtin(__builtin_amdgcn_exp2f)
    return __builtin_amdgcn_exp2f(x);
#else
    return exp2f(x);
#endif
}
__device__ __forceinline__ float frcp(float x) {
#if __has_builtin(__builtin_amdgcn_rcpf)
    return __builtin_amdgcn_rcpf(x);
#else
    return 1.0f / x;
#endif
}

__global__ __launch_bounds__(BLK) void fused_tanh_heads(
    const float* __restrict__ x,     // [B,3]
    const float* __restrict__ W,     // [64,3,3]
    const float* __restrict__ bias,  // [64,3]
    const float* __restrict__ c_rho, // [64]
    const float* __restrict__ c_p,   // [64]
    const float* __restrict__ c_u,   // [64]
    float* __restrict__ out,         // [3*B]
    int B)
{
    // Per-n record: 16 floats = {K*W[9], K*b[3], crho, cp, cu, pad}.
    __shared__ float sc[NN * 16];
    const int t = threadIdx.x;
    // Conflict-free fill: lane t writes idx = t + 256k (bank = t%32, stride 256).
    #pragma unroll
    for (int k = 0; k < 4; ++k) {
        const int idx = t + BLK * k;   // 0..1023
        const int n = idx >> 4;
        const int o = idx & 15;
        const float K = 2.8853900817779268f;  // 2*log2(e)
        float v;
        if (o < 9)       v = W[n * 9 + o] * K;
        else if (o < 12) v = bias[n * 3 + (o - 9)] * K;
        else if (o == 12) v = c_rho[n];
        else if (o == 13) v = c_p[n];
        else if (o == 14) v = c_u[n];
        else              v = 0.0f;
        sc[idx] = v;
    }
    __syncthreads();

    // C_k = sum_n c_k[n] via wave butterfly on coalesced global reads.
    float C0 = c_rho[t & 63], C1 = c_p[t & 63], C2 = c_u[t & 63];
    #pragma unroll
    for (int o = 1; o < 64; o <<= 1) {
        C0 += __shfl_xor(C0, o);
        C1 += __shfl_xor(C1, o);
        C2 += __shfl_xor(C2, o);
    }

    const int base = blockIdx.x * (BLK * RPT) + t;

    int   rows[RPT];
    float xs[RPT][3];
    #pragma unroll
    for (int i = 0; i < RPT; ++i) {
        const int r = base + i * BLK;
        rows[i] = r;
        const bool ok = (r < B);
        xs[i][0] = ok ? x[r * 3 + 0] : 0.0f;
        xs[i][1] = ok ? x[r * 3 + 1] : 0.0f;
        xs[i][2] = ok ? x[r * 3 + 2] : 0.0f;
    }

    float acc[RPT][3];
    #pragma unroll
    for (int i = 0; i < RPT; ++i) { acc[i][0] = acc[i][1] = acc[i][2] = 0.0f; }

    const float4* q4 = (const float4*)sc;
    #pragma unroll 2
    for (int n = 0; n < NN; ++n) {
        const float4 q0 = q4[n * 4 + 0];  // W0 W1 W2 W3   (xK)
        const float4 q1 = q4[n * 4 + 1];  // W4 W5 W6 W7   (xK)
        const float4 q2 = q4[n * 4 + 2];  // W8 b0 b1 b2   (xK)
        const float4 q3 = q4[n * 4 + 3];  // crho cp cu pad
        #pragma unroll
        for (int i = 0; i < RPT; ++i) {
            const float x0 = xs[i][0], x1 = xs[i][1], x2 = xs[i][2];
            const float h0 = fmaf(x2, q0.z, fmaf(x1, q0.y, fmaf(x0, q0.x, q2.y)));
            const float h1 = fmaf(x2, q1.y, fmaf(x1, q1.x, fmaf(x0, q0.w, q2.z)));
            const float h2 = fmaf(x2, q2.x, fmaf(x1, q1.w, fmaf(x0, q1.z, q2.w)));
            const float a0 = fexp2(h0) + 1.0f;   // in (1, ~2^16) — no overflow
            const float a1 = fexp2(h1) + 1.0f;
            const float a2 = fexp2(h2) + 1.0f;
            const float m  = a0 * a1;
            const float rr = frcp(m * a2);       // product <= ~1.4e14, safe
            const float i2 = m  * rr;
            const float s  = a2 * rr;
            const float i0 = a1 * s;
            const float i1 = a0 * s;
            acc[i][0] = fmaf(i0, q3.x, acc[i][0]);
            acc[i][1] = fmaf(i1, q3.y, acc[i][1]);
            acc[i][2] = fmaf(i2, q3.z, acc[i][2]);
        }
    }

    #pragma unroll
    for (int i = 0; i < RPT; ++i) {
        const int r = rows[i];
        if (r < B) {
            out[r]         = fmaf(-2.0f, acc[i][0], C0);
            out[B + r]     = fmaf(-2.0f, acc[i][1], C1);
            out[2 * B + r] = fmaf(-2.0f, acc[i][2], C2);
        }
    }
}

extern "C" void kernel_launch(void* const* d_in, const int* in_sizes, int n_in,
                              void* d_out, int out_size, void* d_ws, size_t ws_size,
                              hipStream_t stream) {
    (void)d_ws; (void)ws_size; (void)n_in; (void)out_size;
    const float* x     = (const float*)d_in[0];
    const float* W     = (const float*)d_in[1];
    const float* bias  = (const float*)d_in[2];
    const float* c_rho = (const float*)d_in[3];
    const float* c_p   = (const float*)d_in[4];
    const float* c_u   = (const float*)d_in[5];
    float* out = (float*)d_out;

    const int B = in_sizes[0] / 3;
    const int rows_per_block = BLK * RPT;
    const int grid = (B + rows_per_block - 1) / rows_per_block;

    fused_tanh_heads<<<grid, BLK, 0, stream>>>(x, W, bias, c_rho, c_p, c_u, out, B);
}

// Round 8
// 115.076 us; speedup vs baseline: 1.2345x; 1.0954x over previous
//
#include <hip/hip_runtime.h>

// B=1e6 rows, N=64 heads, D=3.
// u[b,n,k] = tanh(x[b,:]·W[n,k,:] + bias[n,k]); out_k[b] = sum_n u[b,n,k]*c_k[n].
// d_out: [0..B)=rho, [B..2B)=p, [2B..3B)=u  (f32).
//
// tanh(h) = 1 - 2/(1+exp2(K*h)), K=2*log2(e), K folded into W,b at LDS-fill.
// C-fold: out_k = C_k - 2*sum_n c_k[n]*inv_k[n], C_k = sum_n c_k[n] (butterfly).
// One rcp per row serves all 3 channels: inv_i = (prod_{j!=i} a_j)*rcp(prod a_j).
// Structure identical to the measured-best R2 kernel (54.4 us) except:
//   (a) 3 packed T-FMAs deleted via C-fold, (b) conflict-free LDS fill.

#define NN   64
#define RPT  2
#define BLK  256

typedef float f2 __attribute__((ext_vector_type(2)));

__device__ __forceinline__ f2 mk2(float a, float b) { f2 r; r.x = a; r.y = b; return r; }
__device__ __forceinline__ f2 pkfma(f2 a, f2 b, f2 c) { return __builtin_elementwise_fma(a, b, c); }

__device__ __forceinline__ float fexp2(float x) {
#if __has_builtin(__builtin_amdgcn_exp2f)
    return __builtin_amdgcn_exp2f(x);
#else
    return exp2f(x);
#endif
}
__device__ __forceinline__ float frcp(float x) {
#if __has_builtin(__builtin_amdgcn_rcpf)
    return __builtin_amdgcn_rcpf(x);
#else
    return 1.0f / x;
#endif
}

__global__ __launch_bounds__(BLK) void fused_tanh_heads(
    const float* __restrict__ x,     // [B,3]
    const float* __restrict__ W,     // [64,3,3]
    const float* __restrict__ bias,  // [64,3]
    const float* __restrict__ c_rho, // [64]
    const float* __restrict__ c_p,   // [64]
    const float* __restrict__ c_u,   // [64]
    float* __restrict__ out,         // [3*B]
    int B)
{
    // Per-n record: 32 floats, pair-splatted: {K*W[9] x2, K*b[3] x2, crho x2,
    // cp x2, cu x2, pad x2} -> 8 float4 broadcast reads per n.
    __shared__ float sc[NN * 32];
    const int t = threadIdx.x;
    // Conflict-free fill: lane t writes idx = t + 256k (bank = t%32).
    #pragma unroll
    for (int k = 0; k < 8; ++k) {
        const int idx = t + BLK * k;   // 0..2047
        const int n = idx >> 5;
        const int o = idx & 31;
        const float K = 2.8853900817779268f;  // 2*log2(e)
        float v;
        if (o < 18)      v = W[n * 9 + (o >> 1)] * K;
        else if (o < 24) v = bias[n * 3 + ((o - 18) >> 1)] * K;
        else if (o < 26) v = c_rho[n];
        else if (o < 28) v = c_p[n];
        else if (o < 30) v = c_u[n];
        else             v = 0.0f;
        sc[idx] = v;
    }
    __syncthreads();

    // C_k = sum_n c_k[n] (wave butterfly; every lane ends with the full sum).
    float C0 = c_rho[t & 63], C1 = c_p[t & 63], C2 = c_u[t & 63];
    #pragma unroll
    for (int o = 1; o < 64; o <<= 1) {
        C0 += __shfl_xor(C0, o);
        C1 += __shfl_xor(C1, o);
        C2 += __shfl_xor(C2, o);
    }

    const int r0 = blockIdx.x * (BLK * RPT) + t;
    const int r1 = r0 + BLK;
    const bool ok0 = (r0 < B), ok1 = (r1 < B);

    const f2 X0 = mk2(ok0 ? x[r0 * 3 + 0] : 0.0f, ok1 ? x[r1 * 3 + 0] : 0.0f);
    const f2 X1 = mk2(ok0 ? x[r0 * 3 + 1] : 0.0f, ok1 ? x[r1 * 3 + 1] : 0.0f);
    const f2 X2 = mk2(ok0 ? x[r0 * 3 + 2] : 0.0f, ok1 ? x[r1 * 3 + 2] : 0.0f);

    f2 acc0 = mk2(0.0f, 0.0f), acc1 = acc0, acc2 = acc0;

    const float4* q4 = (const float4*)sc;
    #pragma unroll 2
    for (int n = 0; n < NN; ++n) {
        const float4 Q0 = q4[n * 8 + 0];  // w00 w01
        const float4 Q1 = q4[n * 8 + 1];  // w02 w10
        const float4 Q2 = q4[n * 8 + 2];  // w11 w12
        const float4 Q3 = q4[n * 8 + 3];  // w20 w21
        const float4 Q4 = q4[n * 8 + 4];  // w22 b0
        const float4 Q5 = q4[n * 8 + 5];  // b1  b2
        const float4 Q6 = q4[n * 8 + 6];  // crho cp
        const float4 Q7 = q4[n * 8 + 7];  // cu  pad

        f2 h0 = pkfma(X2, mk2(Q1.x, Q1.y),
                 pkfma(X1, mk2(Q0.z, Q0.w),
                  pkfma(X0, mk2(Q0.x, Q0.y), mk2(Q4.z, Q4.w))));
        f2 h1 = pkfma(X2, mk2(Q2.z, Q2.w),
                 pkfma(X1, mk2(Q2.x, Q2.y),
                  pkfma(X0, mk2(Q1.z, Q1.w), mk2(Q5.x, Q5.y))));
        f2 h2 = pkfma(X2, mk2(Q4.x, Q4.y),
                 pkfma(X1, mk2(Q3.z, Q3.w),
                  pkfma(X0, mk2(Q3.x, Q3.y), mk2(Q5.z, Q5.w))));

        const float a00 = fexp2(h0.x) + 1.0f, a01 = fexp2(h0.y) + 1.0f;
        const float a10 = fexp2(h1.x) + 1.0f, a11 = fexp2(h1.y) + 1.0f;
        const float a20 = fexp2(h2.x) + 1.0f, a21 = fexp2(h2.y) + 1.0f;

        // one rcp per row for all 3 channels
        const float m0  = a00 * a10;
        const float rA  = frcp(m0 * a20);
        const float i20 = m0 * rA;
        const float s0  = a20 * rA;
        const float i00 = a10 * s0;
        const float i10 = a00 * s0;
        const float m1  = a01 * a11;
        const float rB  = frcp(m1 * a21);
        const float i21 = m1 * rB;
        const float s1  = a21 * rB;
        const float i01 = a11 * s1;
        const float i11 = a01 * s1;

        // acc += inv * c   (tanh fold lives in the epilogue: out = C - 2*acc)
        acc0 = pkfma(mk2(i00, i01), mk2(Q6.x, Q6.y), acc0);
        acc1 = pkfma(mk2(i10, i11), mk2(Q6.z, Q6.w), acc1);
        acc2 = pkfma(mk2(i20, i21), mk2(Q7.x, Q7.y), acc2);
    }

    if (ok0) {
        out[r0]         = fmaf(-2.0f, acc0.x, C0);
        out[B + r0]     = fmaf(-2.0f, acc1.x, C1);
        out[2 * B + r0] = fmaf(-2.0f, acc2.x, C2);
    }
    if (ok1) {
        out[r1]         = fmaf(-2.0f, acc0.y, C0);
        out[B + r1]     = fmaf(-2.0f, acc1.y, C1);
        out[2 * B + r1] = fmaf(-2.0f, acc2.y, C2);
    }
}

extern "C" void kernel_launch(void* const* d_in, const int* in_sizes, int n_in,
                              void* d_out, int out_size, void* d_ws, size_t ws_size,
                              hipStream_t stream) {
    (void)d_ws; (void)ws_size; (void)n_in; (void)out_size;
    const float* x     = (const float*)d_in[0];
    const float* W     = (const float*)d_in[1];
    const float* bias  = (const float*)d_in[2];
    const float* c_rho = (const float*)d_in[3];
    const float* c_p   = (const float*)d_in[4];
    const float* c_u   = (const float*)d_in[5];
    float* out = (float*)d_out;

    const int B = in_sizes[0] / 3;
    const int rows_per_block = BLK * RPT;
    const int grid = (B + rows_per_block - 1) / rows_per_block;

    fused_tanh_heads<<<grid, BLK, 0, stream>>>(x, W, bias, c_rho, c_p, c_u, out, B);
}

// Round 9
// 113.819 us; speedup vs baseline: 1.2481x; 1.0111x over previous
//
#include <hip/hip_runtime.h>

// B=1e6 rows, N=64 heads, D=3.
// u[b,n,k] = tanh(x[b,:]·W[n,k,:] + bias[n,k]); out_k[b] = sum_n u[b,n,k]*c_k[n].
// d_out: [0..B)=rho, [B..2B)=p, [2B..3B)=u  (f32).
//
// tanh(h) = 1 - 2/(1+exp2(K*h)), K=2*log2(e), K folded into W,b.
// C-fold: out_k = C_k - 2*sum_n c_k[n]*inv_k[n], C_k = sum_n c_k[n].
// One rcp per row serves all 3 channels (cofactor trick).
//
// KEY CHANGE vs R2/R7: constants are wave-uniform -> move them OUT of LDS
// into a d_ws table read at loop-uniform addresses. Compiler emits s_load
// (SMEM pipe) into SGPRs; v_pk_fma_f32 consumes the SGPR pair directly.
// Zero LDS in the main kernel: no ds_read pipe contention, no syncthreads.

#define NN   64
#define RPT  2
#define BLK  256

typedef float f2 __attribute__((ext_vector_type(2)));

__device__ __forceinline__ f2 mk2(float a, float b) { f2 r; r.x = a; r.y = b; return r; }
__device__ __forceinline__ f2 pkfma(f2 a, f2 b, f2 c) { return __builtin_elementwise_fma(a, b, c); }

__device__ __forceinline__ float fexp2(float x) {
#if __has_builtin(__builtin_amdgcn_exp2f)
    return __builtin_amdgcn_exp2f(x);
#else
    return exp2f(x);
#endif
}
__device__ __forceinline__ float frcp(float x) {
#if __has_builtin(__builtin_amdgcn_rcpf)
    return __builtin_amdgcn_rcpf(x);
#else
    return 1.0f / x;
#endif
}

// ws layout (floats): [n*32 .. n*32+32) = pair-splatted record for head n:
//   {K*W[9] x2, K*b[3] x2, crho x2, cp x2, cu x2, pad x2}
// [2048..2051) = C0, C1, C2 (sum of c over n).
__global__ __launch_bounds__(64) void setup_tab(
    const float* __restrict__ W, const float* __restrict__ bias,
    const float* __restrict__ c_rho, const float* __restrict__ c_p,
    const float* __restrict__ c_u, float* __restrict__ ws)
{
    const int t = threadIdx.x;            // 64 threads == 64 heads == 1 wave
    const float K = 2.8853900817779268f;  // 2*log2(e)
    float* rec = ws + t * 32;
    #pragma unroll
    for (int j = 0; j < 9; ++j) {
        const float w = W[t * 9 + j] * K;
        rec[2 * j] = w; rec[2 * j + 1] = w;
    }
    #pragma unroll
    for (int k = 0; k < 3; ++k) {
        const float b = bias[t * 3 + k] * K;
        rec[18 + 2 * k] = b; rec[19 + 2 * k] = b;
    }
    const float cr = c_rho[t], cp = c_p[t], cu = c_u[t];
    rec[24] = cr; rec[25] = cr;
    rec[26] = cp; rec[27] = cp;
    rec[28] = cu; rec[29] = cu;
    rec[30] = 0.0f; rec[31] = 0.0f;

    float C0 = cr, C1 = cp, C2 = cu;
    #pragma unroll
    for (int o = 1; o < 64; o <<= 1) {
        C0 += __shfl_xor(C0, o);
        C1 += __shfl_xor(C1, o);
        C2 += __shfl_xor(C2, o);
    }
    if (t == 0) { ws[2048] = C0; ws[2049] = C1; ws[2050] = C2; }
}

__global__ __launch_bounds__(BLK) void fused_tanh_heads(
    const float* __restrict__ x,    // [B,3]
    const float* __restrict__ ws,   // table from setup_tab
    float* __restrict__ out,        // [3*B]
    int B)
{
    const int t = threadIdx.x;
    // Uniform scalars -> s_load into SGPRs.
    const float C0 = ws[2048], C1 = ws[2049], C2 = ws[2050];

    const int r0 = blockIdx.x * (BLK * RPT) + t;
    const int r1 = r0 + BLK;
    const bool ok0 = (r0 < B), ok1 = (r1 < B);

    const f2 X0 = mk2(ok0 ? x[r0 * 3 + 0] : 0.0f, ok1 ? x[r1 * 3 + 0] : 0.0f);
    const f2 X1 = mk2(ok0 ? x[r0 * 3 + 1] : 0.0f, ok1 ? x[r1 * 3 + 1] : 0.0f);
    const f2 X2 = mk2(ok0 ? x[r0 * 3 + 2] : 0.0f, ok1 ? x[r1 * 3 + 2] : 0.0f);

    f2 acc0 = mk2(0.0f, 0.0f), acc1 = acc0, acc2 = acc0;
    const f2 one2 = mk2(1.0f, 1.0f);

    const f2* __restrict__ tab = (const f2*)ws;   // 16 f2 per head record
    #pragma unroll 2
    for (int n = 0; n < NN; ++n) {
        const f2* __restrict__ r = tab + n * 16;
        const f2 w0 = r[0], w1 = r[1], w2 = r[2];     // row k=0 weights (x2)
        const f2 w3 = r[3], w4 = r[4], w5 = r[5];     // row k=1
        const f2 w6 = r[6], w7 = r[7], w8 = r[8];     // row k=2
        const f2 b0 = r[9], b1 = r[10], b2 = r[11];
        const f2 cr = r[12], cp = r[13], cu = r[14];

        f2 h0 = pkfma(X2, w2, pkfma(X1, w1, pkfma(X0, w0, b0)));
        f2 h1 = pkfma(X2, w5, pkfma(X1, w4, pkfma(X0, w3, b1)));
        f2 h2 = pkfma(X2, w8, pkfma(X1, w7, pkfma(X0, w6, b2)));

        const f2 a0 = mk2(fexp2(h0.x), fexp2(h0.y)) + one2;
        const f2 a1 = mk2(fexp2(h1.x), fexp2(h1.y)) + one2;
        const f2 a2 = mk2(fexp2(h2.x), fexp2(h2.y)) + one2;

        // one rcp per row (rows live in the two f2 lanes)
        const f2 m = a0 * a1;
        const f2 T = m * a2;                    // (t_row0, t_row1)
        const f2 R = mk2(frcp(T.x), frcp(T.y));
        const f2 i2 = m * R;
        const f2 s  = a2 * R;
        const f2 i0 = a1 * s;
        const f2 i1 = a0 * s;

        acc0 = pkfma(i0, cr, acc0);
        acc1 = pkfma(i1, cp, acc1);
        acc2 = pkfma(i2, cu, acc2);
    }

    if (ok0) {
        out[r0]         = fmaf(-2.0f, acc0.x, C0);
        out[B + r0]     = fmaf(-2.0f, acc1.x, C1);
        out[2 * B + r0] = fmaf(-2.0f, acc2.x, C2);
    }
    if (ok1) {
        out[r1]         = fmaf(-2.0f, acc0.y, C0);
        out[B + r1]     = fmaf(-2.0f, acc1.y, C1);
        out[2 * B + r1] = fmaf(-2.0f, acc2.y, C2);
    }
}

extern "C" void kernel_launch(void* const* d_in, const int* in_sizes, int n_in,
                              void* d_out, int out_size, void* d_ws, size_t ws_size,
                              hipStream_t stream) {
    (void)ws_size; (void)n_in; (void)out_size;
    const float* x     = (const float*)d_in[0];
    const float* W     = (const float*)d_in[1];
    const float* bias  = (const float*)d_in[2];
    const float* c_rho = (const float*)d_in[3];
    const float* c_p   = (const float*)d_in[4];
    const float* c_u   = (const float*)d_in[5];
    float* out = (float*)d_out;
    float* ws  = (float*)d_ws;   // needs 2051*4 bytes

    const int B = in_sizes[0] / 3;
    const int rows_per_block = BLK * RPT;
    const int grid = (B + rows_per_block - 1) / rows_per_block;

    setup_tab<<<1, 64, 0, stream>>>(W, bias, c_rho, c_p, c_u, ws);
    fused_tanh_heads<<<grid, BLK, 0, stream>>>(x, ws, out, B);
}